// Round 2
// baseline (33452.335 us; speedup 1.0000x reference)
//
#include <hip/hip_runtime.h>
#include <hip/hip_bf16.h>

#define TPB   256
#define D     1024
#define D2    2048
#define S_LEN 2048
#define RANK  32
#define DFF   2816
#define EPS_F 1.1920929e-07f

typedef unsigned short u16;
typedef unsigned int   u32;

__device__ __forceinline__ void unpack2(u32 u, float& lo, float& hi) {
    union { float f; u32 i; } a, b;
    a.i = u << 16;           // element 0 (low 16 bits)
    b.i = u & 0xFFFF0000u;   // element 1 (high 16 bits)
    lo = a.f; hi = b.f;
}

struct f8 { float v[8]; };

// load 8 consecutive elements (as fp32) starting at element offset `off`
template<bool F32>
__device__ __forceinline__ f8 load8(const void* base, size_t off) {
    f8 r;
    if (F32) {
        const float4* p = (const float4*)((const float*)base + off);
        float4 a = p[0], b = p[1];
        r.v[0]=a.x; r.v[1]=a.y; r.v[2]=a.z; r.v[3]=a.w;
        r.v[4]=b.x; r.v[5]=b.y; r.v[6]=b.z; r.v[7]=b.w;
    } else {
        uint4 u = *(const uint4*)((const u16*)base + off);
        unpack2(u.x, r.v[0], r.v[1]); unpack2(u.y, r.v[2], r.v[3]);
        unpack2(u.z, r.v[4], r.v[5]); unpack2(u.w, r.v[6], r.v[7]);
    }
    return r;
}

template<bool F32>
__device__ __forceinline__ void load4(const void* base, size_t off,
                                      float& a0, float& a1, float& a2, float& a3) {
    if (F32) {
        float4 v = *(const float4*)((const float*)base + off);
        a0 = v.x; a1 = v.y; a2 = v.z; a3 = v.w;
    } else {
        uint2 v = *(const uint2*)((const u16*)base + off);
        unpack2(v.x, a0, a1); unpack2(v.y, a2, a3);
    }
}

template<bool F32>
__device__ __forceinline__ void store1(void* base, size_t off, float v) {
    if (F32) ((float*)base)[off] = v;
    else     ((__hip_bfloat16*)base)[off] = __float2bfloat16(v);
}

__device__ __forceinline__ float dot8g(const f8& w, const float* __restrict__ x) {
    return w.v[0]*x[0] + w.v[1]*x[1] + w.v[2]*x[2] + w.v[3]*x[3]
         + w.v[4]*x[4] + w.v[5]*x[5] + w.v[6]*x[6] + w.v[7]*x[7];
}

__device__ __forceinline__ float wave_reduce(float v) {
    #pragma unroll
    for (int off = 1; off < 64; off <<= 1)
        v += __shfl_xor(v, off, 64);
    return v;
}

__device__ __forceinline__ float block_reduce(float v, float* red) {
    v = wave_reduce(v);
    if ((threadIdx.x & 63) == 0) red[threadIdx.x >> 6] = v;
    __syncthreads();
    float r = red[0] + red[1] + red[2] + red[3];
    __syncthreads();
    return r;
}

// ---------------- dtype probe: 1 block ----------------
// Interprets the first 256 u32 words of x as 512 bf16 halves. If storage is
// fp32, the low mantissa halves decode as random-exponent bf16 -> ~45% have
// |v|>1e4 (incl. inf/nan). If storage is bf16, all values ~N(0,1) -> none.
__global__ void probe_kernel(const u32* __restrict__ x, int* __restrict__ flag) {
    __shared__ int cnt;
    int tid = threadIdx.x;
    if (tid == 0) cnt = 0;
    __syncthreads();
    u32 u = x[tid];
    float lo, hi; unpack2(u, lo, hi);
    int c = 0;
    if (!(fabsf(lo) < 1e4f)) c++;   // NaN-safe: NaN fails the < test
    if (!(fabsf(hi) < 1e4f)) c++;
    if (c) atomicAdd(&cnt, c);
    __syncthreads();
    if (tid == 0) *flag = (cnt > 16) ? 1 : 0;   // 1 => fp32 storage
}

// ---------------- iteration kernel: one workgroup per token ----------------
template<bool F32>
__global__ __launch_bounds__(TPB) void iter_kernel(
    const int* __restrict__ flag,
    const void* __restrict__ hin, void* __restrict__ hout,
    const void* __restrict__ Wfg, const void* __restrict__ Afg, const void* __restrict__ Bfg,
    const void* __restrict__ Wgu, const void* __restrict__ Agu, const void* __restrict__ Bgu)
{
    if ((*flag != 0) != F32) return;   // wrong dtype variant: no-op

    __shared__ float comb[D2];
    __shared__ float hcur[D];
    __shared__ float tlow[2 * RANK];
    __shared__ float red[8];

    const int tid   = threadIdx.x;
    const int token = blockIdx.x;
    const int s     = token & (S_LEN - 1);

    // ---- rmsnorm(h_t) ----
    {
        float a0,a1,a2,a3;
        load4<F32>(hin, (size_t)token * D + tid * 4, a0, a1, a2, a3);
        float ss = block_reduce(a0*a0 + a1*a1 + a2*a2 + a3*a3, red);
        float sc = rsqrtf(ss * (1.0f / D) + EPS_F);
        int base = tid * 4;
        comb[base+0] = a0 * sc; comb[base+1] = a1 * sc;
        comb[base+2] = a2 * sc; comb[base+3] = a3 * sc;
        hcur[base+0] = a0; hcur[base+1] = a1;
        hcur[base+2] = a2; hcur[base+3] = a3;
    }

    // ---- shifted = rmsnorm(h_{t-1}) (zeros at s==0); s uniform per block ----
    {
        int base = tid * 4;
        if (s > 0) {
            float b0,b1,b2,b3;
            load4<F32>(hin, (size_t)(token - 1) * D + tid * 4, b0, b1, b2, b3);
            float ss = block_reduce(b0*b0 + b1*b1 + b2*b2 + b3*b3, red);
            float sc = rsqrtf(ss * (1.0f / D) + EPS_F);
            comb[D+base+0] = b0 * sc; comb[D+base+1] = b1 * sc;
            comb[D+base+2] = b2 * sc; comb[D+base+3] = b3 * sc;
        } else {
            comb[D+base+0] = 0.f; comb[D+base+1] = 0.f;
            comb[D+base+2] = 0.f; comb[D+base+3] = 0.f;
        }
    }
    __syncthreads();

    // ---- low-rank t = B @ comb : 64 rows of length 2048, 4 threads/row ----
    {
        int g   = tid >> 2;
        int sub = tid & 3;
        const void* Bm = (g < RANK) ? Bfg : Bgu;
        size_t roff = (size_t)((g < RANK) ? g : g - RANK) * D2 + sub * 512;
        const float* cp = comb + sub * 512;
        float acc = 0.f;
        #pragma unroll 8
        for (int i = 0; i < 64; ++i)
            acc += dot8g(load8<F32>(Bm, roff + i * 8), cp + i * 8);
        acc += __shfl_xor(acc, 1, 64);
        acc += __shfl_xor(acc, 2, 64);
        if (sub == 0) tlow[g] = acc;
    }
    __syncthreads();

    // ---- block-diagonal mains + epilogue: 4 outputs per thread ----
    #pragma unroll 1
    for (int m = 0; m < 4; ++m) {
        int o = tid + (m << 8);
        int b = o >> 7;
        const float* xb = comb + (b << 8);
        float accf = 0.f, accg = 0.f;
        #pragma unroll 8
        for (int i = 0; i < 32; ++i) {
            accf += dot8g(load8<F32>(Wfg, (size_t)o * 256 + i * 8), xb + i * 8);
            accg += dot8g(load8<F32>(Wgu, (size_t)o * 256 + i * 8), xb + i * 8);
        }
        #pragma unroll
        for (int i = 0; i < 4; ++i) {
            accf += dot8g(load8<F32>(Afg, (size_t)o * RANK + i * 8), tlow + i * 8);
            accg += dot8g(load8<F32>(Agu, (size_t)o * RANK + i * 8), tlow + RANK + i * 8);
        }
        float gate = 1.f / (1.f + __expf(-accf));
        float hnew = hcur[o] + gate * accg;
        store1<F32>(hout, (size_t)token * D + o, hnew);
    }
}

// ---------------- final kernel: one workgroup per token ----------------
template<bool F32>
__global__ __launch_bounds__(TPB) void final_kernel(
    const int* __restrict__ flag,
    const void* __restrict__ hin, void* __restrict__ out,
    const void* __restrict__ Wg, const void* __restrict__ Ag, const void* __restrict__ Bg,
    const void* __restrict__ Wf, const void* __restrict__ Af, const void* __restrict__ Bf,
    const void* __restrict__ Wp, const void* __restrict__ Ap, const void* __restrict__ Bp)
{
    if ((*flag != 0) != F32) return;

    __shared__ float z[D];
    __shared__ float hcur[D];
    __shared__ float ff[DFF];
    __shared__ float tg[RANK], tf[RANK], tp[RANK];
    __shared__ float red[8];

    const int tid   = threadIdx.x;
    const int token = blockIdx.x;

    // ---- rmsnorm ----
    {
        float a0,a1,a2,a3;
        load4<F32>(hin, (size_t)token * D + tid * 4, a0, a1, a2, a3);
        float ss = block_reduce(a0*a0 + a1*a1 + a2*a2 + a3*a3, red);
        float sc = rsqrtf(ss * (1.0f / D) + EPS_F);
        int base = tid * 4;
        z[base+0] = a0 * sc; z[base+1] = a1 * sc;
        z[base+2] = a2 * sc; z[base+3] = a3 * sc;
        hcur[base+0] = a0; hcur[base+1] = a1;
        hcur[base+2] = a2; hcur[base+3] = a3;
    }
    __syncthreads();

    // ---- low-rank over z: 64 rows of 1024, 4 threads/row ----
    {
        int g   = tid >> 2;
        int sub = tid & 3;
        const void* Bm = (g < RANK) ? Bg : Bf;
        size_t roff = (size_t)((g < RANK) ? g : g - RANK) * D + sub * 256;
        const float* cp = z + sub * 256;
        float acc = 0.f;
        #pragma unroll 8
        for (int i = 0; i < 32; ++i)
            acc += dot8g(load8<F32>(Bm, roff + i * 8), cp + i * 8);
        acc += __shfl_xor(acc, 1, 64);
        acc += __shfl_xor(acc, 2, 64);
        if (sub == 0) { if (g < RANK) tg[g] = acc; else tf[g - RANK] = acc; }
    }
    __syncthreads();

    // ---- ff: 2816 outputs = 11 * 256 ----
    #pragma unroll 1
    for (int m = 0; m < 11; ++m) {
        int j = tid + (m << 8);
        int b = j / 352;
        const float* xb = z + b * 128;
        float ag = 0.f, af = 0.f;
        #pragma unroll
        for (int i = 0; i < 16; ++i) {
            ag += dot8g(load8<F32>(Wg, (size_t)j * 128 + i * 8), xb + i * 8);
            af += dot8g(load8<F32>(Wf, (size_t)j * 128 + i * 8), xb + i * 8);
        }
        #pragma unroll
        for (int i = 0; i < 4; ++i) {
            ag += dot8g(load8<F32>(Ag, (size_t)j * RANK + i * 8), tg + i * 8);
            af += dot8g(load8<F32>(Af, (size_t)j * RANK + i * 8), tf + i * 8);
        }
        float sg = ag / (1.f + __expf(-ag));   // silu
        ff[j] = sg * af;
    }
    __syncthreads();

    // ---- low-rank over ff: 32 rows of 2816, 8 threads/row ----
    {
        int g   = tid >> 3;
        int sub = tid & 7;
        size_t roff = (size_t)g * DFF + sub * 352;
        const float* cp = ff + sub * 352;
        float acc = 0.f;
        #pragma unroll 4
        for (int i = 0; i < 44; ++i)
            acc += dot8g(load8<F32>(Bp, roff + i * 8), cp + i * 8);
        acc += __shfl_xor(acc, 1, 64);
        acc += __shfl_xor(acc, 2, 64);
        acc += __shfl_xor(acc, 4, 64);
        if (sub == 0) tp[g] = acc;
    }
    __syncthreads();

    // ---- out: 1024 outputs, block_in = 352 ----
    #pragma unroll 1
    for (int m = 0; m < 4; ++m) {
        int o = tid + (m << 8);
        int b = o >> 7;
        const float* xb = ff + b * 352;
        float acc = 0.f;
        #pragma unroll 4
        for (int i = 0; i < 44; ++i)
            acc += dot8g(load8<F32>(Wp, (size_t)o * 352 + i * 8), xb + i * 8);
        #pragma unroll
        for (int i = 0; i < 4; ++i)
            acc += dot8g(load8<F32>(Ap, (size_t)o * RANK + i * 8), tp + i * 8);
        store1<F32>(out, (size_t)token * D + o, hcur[o] + acc);
    }
}

extern "C" void kernel_launch(void* const* d_in, const int* in_sizes, int n_in,
                              void* d_out, int out_size, void* d_ws, size_t ws_size,
                              hipStream_t stream) {
    const void* x     = d_in[0];
    const void* fg_W  = d_in[1];
    const void* fg_A  = d_in[2];
    const void* fg_B  = d_in[3];
    const void* gu_W  = d_in[4];
    const void* gu_A  = d_in[5];
    const void* gu_B  = d_in[6];
    const void* ffg_W = d_in[7];
    const void* ffg_A = d_in[8];
    const void* ffg_B = d_in[9];
    const void* fff_W = d_in[10];
    const void* fff_A = d_in[11];
    const void* fff_B = d_in[12];
    const void* ffp_W = d_in[13];
    const void* ffp_A = d_in[14];
    const void* ffp_B = d_in[15];

    int*  flag = (int*)d_ws;
    void* h1   = (void*)((char*)d_ws + 1024);   // up to 64 MiB (fp32 case)
    void* hout = d_out;

    const int n_tok = 8 * S_LEN;   // 16384

    probe_kernel<<<1, 256, 0, stream>>>((const u32*)x, flag);

    // ping-pong: x -> h1 -> out -> h1 -> out, then final(out -> out in place)
    // Launch both dtype variants per stage; the wrong one early-exits on flag.
    #define ITER(SRC, DST) \
        iter_kernel<false><<<n_tok, TPB, 0, stream>>>(flag, SRC, DST, fg_W, fg_A, fg_B, gu_W, gu_A, gu_B); \
        iter_kernel<true ><<<n_tok, TPB, 0, stream>>>(flag, SRC, DST, fg_W, fg_A, fg_B, gu_W, gu_A, gu_B);

    ITER(x,    h1)
    ITER(h1,   hout)
    ITER(hout, h1)
    ITER(h1,   hout)
    #undef ITER

    final_kernel<false><<<n_tok, TPB, 0, stream>>>(flag, hout, hout,
                                                   ffg_W, ffg_A, ffg_B,
                                                   fff_W, fff_A, fff_B,
                                                   ffp_W, ffp_A, ffp_B);
    final_kernel<true ><<<n_tok, TPB, 0, stream>>>(flag, hout, hout,
                                                   ffg_W, ffg_A, ffg_B,
                                                   fff_W, fff_A, fff_B,
                                                   ffp_W, ffp_A, ffp_B);
}